// Round 3
// baseline (170.918 us; speedup 1.0000x reference)
//
#include <hip/hip_runtime.h>
#include <math.h>

#define FT_OUT 256
#define VFT 640
#define CAP 96  // per-row bucket capacity; Poisson(32) max ~56-60, 96 = +11 sigma

typedef _Float16 half4_t __attribute__((ext_vector_type(4)));
typedef _Float16 half8_t __attribute__((ext_vector_type(8)));

// ---- W2h[col][o] = (half)(ft_w[o][col] + fft_w[o][col%640]) ; LDS-tiled transpose ----
__global__ __launch_bounds__(256) void build_w2_k(const float* __restrict__ ft_w,
                                                  const float* __restrict__ fft_w,
                                                  _Float16* __restrict__ W2h, int ft_in) {
    __shared__ float tile[64][65];  // [out][col]
    int cb = blockIdx.x * 64;   // col base
    int ob = blockIdx.y * 64;   // out base
    // load phase: float4 coalesced reads; 256 threads = 16 rows x 16 col-quads, 4 iters
    int tc4 = threadIdx.x & 15;
    int tr  = threadIdx.x >> 4;
#pragma unroll
    for (int i = 0; i < 4; i++) {
        int o = i * 16 + tr;
        const float4 f = *(const float4*)(ft_w + (size_t)(ob + o) * ft_in + cb + tc4 * 4);
        tile[o][tc4 * 4 + 0] = f.x;
        tile[o][tc4 * 4 + 1] = f.y;
        tile[o][tc4 * 4 + 2] = f.z;
        tile[o][tc4 * 4 + 3] = f.w;
    }
    __syncthreads();
    // store phase: thread -> (col, 8-out chunk); half8 16B stores; fft_w read direct (L2-resident)
    int g  = threadIdx.x & 7;    // out chunk
    int cl = threadIdx.x >> 3;   // 0..31
#pragma unroll
    for (int i = 0; i < 2; i++) {
        int c = i * 32 + cl;
        int col = cb + c;
        int vcol = col % VFT;
        half8_t h;
#pragma unroll
        for (int j = 0; j < 8; j++)
            h[j] = (_Float16)(tile[g * 8 + j][c] + fft_w[(size_t)(ob + g * 8 + j) * VFT + vcol]);
        *(half8_t*)(W2h + (size_t)col * FT_OUT + ob + g * 8) = h;
    }
}

// ---------------- bucket fill: (col, val) appended per row, both sides ----------------
__global__ void fill_slots_k(const int* __restrict__ stm, const int* __restrict__ nstm,
                             const float* __restrict__ vals, int nnz,
                             int* __restrict__ cnt_s, int* __restrict__ cnt_n,
                             int2* __restrict__ slot_s, int2* __restrict__ slot_n) {
    int k = blockIdx.x * blockDim.x + threadIdx.x;
    if (k >= nnz) return;
    int vb = __float_as_int(vals[k]);
    {
        int r = stm[k], c = stm[nnz + k];
        int pos = atomicAdd(&cnt_s[r], 1);
        if (pos < CAP) slot_s[(size_t)r * CAP + pos] = make_int2(c, vb);
    }
    {
        int r = nstm[k], c = nstm[nnz + k];
        int pos = atomicAdd(&cnt_n[r], 1);
        if (pos < CAP) slot_n[(size_t)r * CAP + pos] = make_int2(c, vb);
    }
}

// ------------- fused gather + clip + head + sigmoid: one wave per (row, side) -------------
__global__ __launch_bounds__(256) void fused_k(const _Float16* __restrict__ W2h,
    const int* __restrict__ cnt_s, const int2* __restrict__ slot_s,
    const int* __restrict__ cnt_n, const int2* __restrict__ slot_n,
    const float* __restrict__ ft_b, const float* __restrict__ fft_b,
    const float* __restrict__ out_w, const float* __restrict__ out_b,
    float* __restrict__ out, int B) {
    int lane = threadIdx.x & 63;
    int wid  = threadIdx.x >> 6;            // 0..3
    int row  = blockIdx.x * 2 + (wid >> 1); // 2 rows per block
    int side = wid & 1;                     // 0 = stm, 1 = nstm

    const int*  cnt  = side ? cnt_n : cnt_s;
    const int2* slot = (side ? slot_n : slot_s) + (size_t)row * CAP;
    int n = min(cnt[row], CAP);

    const float4 b1 = ((const float4*)ft_b)[lane];
    const float4 b2 = ((const float4*)fft_b)[lane];
    float4 acc = make_float4(b1.x + b2.x, b1.y + b2.y, b1.z + b2.z, b1.w + b2.w);

    int j = 0;
    for (; j + 4 <= n; j += 4) {  // 4 weight loads + 2 slot loads in flight
        const int4 e0 = *(const int4*)(slot + j);
        const int4 e1 = *(const int4*)(slot + j + 2);
        float v0 = __int_as_float(e0.y), v1 = __int_as_float(e0.w);
        float v2 = __int_as_float(e1.y), v3 = __int_as_float(e1.w);
        const half4_t w0 = *(const half4_t*)(W2h + ((size_t)e0.x << 8) + (lane << 2));
        const half4_t w1 = *(const half4_t*)(W2h + ((size_t)e0.z << 8) + (lane << 2));
        const half4_t w2 = *(const half4_t*)(W2h + ((size_t)e1.x << 8) + (lane << 2));
        const half4_t w3 = *(const half4_t*)(W2h + ((size_t)e1.z << 8) + (lane << 2));
        acc.x += v0 * (float)w0[0]; acc.y += v0 * (float)w0[1];
        acc.z += v0 * (float)w0[2]; acc.w += v0 * (float)w0[3];
        acc.x += v1 * (float)w1[0]; acc.y += v1 * (float)w1[1];
        acc.z += v1 * (float)w1[2]; acc.w += v1 * (float)w1[3];
        acc.x += v2 * (float)w2[0]; acc.y += v2 * (float)w2[1];
        acc.z += v2 * (float)w2[2]; acc.w += v2 * (float)w2[3];
        acc.x += v3 * (float)w3[0]; acc.y += v3 * (float)w3[1];
        acc.z += v3 * (float)w3[2]; acc.w += v3 * (float)w3[3];
    }
    for (; j + 2 <= n; j += 2) {
        const int4 e = *(const int4*)(slot + j);
        float v0 = __int_as_float(e.y), v1 = __int_as_float(e.w);
        const half4_t w0 = *(const half4_t*)(W2h + ((size_t)e.x << 8) + (lane << 2));
        const half4_t w1 = *(const half4_t*)(W2h + ((size_t)e.z << 8) + (lane << 2));
        acc.x += v0 * (float)w0[0]; acc.y += v0 * (float)w0[1];
        acc.z += v0 * (float)w0[2]; acc.w += v0 * (float)w0[3];
        acc.x += v1 * (float)w1[0]; acc.y += v1 * (float)w1[1];
        acc.z += v1 * (float)w1[2]; acc.w += v1 * (float)w1[3];
    }
    if (j < n) {
        const int2 e = slot[j];
        float v0 = __int_as_float(e.y);
        const half4_t w0 = *(const half4_t*)(W2h + ((size_t)e.x << 8) + (lane << 2));
        acc.x += v0 * (float)w0[0]; acc.y += v0 * (float)w0[1];
        acc.z += v0 * (float)w0[2]; acc.w += v0 * (float)w0[3];
    }

    acc.x = fminf(fmaxf(acc.x, 0.f), 1.f);
    acc.y = fminf(fmaxf(acc.y, 0.f), 1.f);
    acc.z = fminf(fmaxf(acc.z, 0.f), 1.f);
    acc.w = fminf(fmaxf(acc.w, 0.f), 1.f);

    const float4 w = ((const float4*)out_w)[side * 64 + lane];
    float p = acc.x * w.x + acc.y * w.y + acc.z * w.z + acc.w * w.w;
#pragma unroll
    for (int m = 32; m >= 1; m >>= 1) p += __shfl_xor(p, m, 64);

    __shared__ float part[4];
    if (lane == 0) part[wid] = p;
    __syncthreads();
    if (threadIdx.x < 2) {
        float q = part[threadIdx.x * 2] + part[threadIdx.x * 2 + 1] + out_b[0];
        out[blockIdx.x * 2 + threadIdx.x] = 1.f / (1.f + __expf(-q));
    }
}

extern "C" void kernel_launch(void* const* d_in, const int* in_sizes, int n_in,
                              void* d_out, int out_size, void* d_ws, size_t ws_size,
                              hipStream_t stream) {
    const int*   stm    = (const int*)d_in[0];   // [2, NNZ]: rows then cols
    const int*   nstm   = (const int*)d_in[1];
    const float* values = (const float*)d_in[2];
    const float* ft_w   = (const float*)d_in[4];
    const float* ft_b   = (const float*)d_in[5];
    const float* fft_w  = (const float*)d_in[6];
    const float* fft_b  = (const float*)d_in[7];
    const float* out_w  = (const float*)d_in[8];
    const float* out_b  = (const float*)d_in[9];
    float* out = (float*)d_out;

    int B = out_size;                 // 8192
    int nnz = in_sizes[0] / 2;        // 262144
    int ft_in = in_sizes[4] / FT_OUT; // 40960

    // workspace layout (16B-aligned pieces)
    _Float16* W2h  = (_Float16*)d_ws;                          // ft_in*256 halfs (20 MB)
    int2*  slot_s  = (int2*)(W2h + (size_t)ft_in * FT_OUT);    // B*CAP entries (6 MB)
    int2*  slot_n  = slot_s + (size_t)B * CAP;                 // 6 MB
    int*   cnt_s   = (int*)(slot_n + (size_t)B * CAP);         // B
    int*   cnt_n   = cnt_s + B;                                // B

    hipMemsetAsync(cnt_s, 0, 2 * (size_t)B * sizeof(int), stream);
    build_w2_k<<<dim3(ft_in / 64, FT_OUT / 64), 256, 0, stream>>>(ft_w, fft_w, W2h, ft_in);
    fill_slots_k<<<(nnz + 255) / 256, 256, 0, stream>>>(stm, nstm, values, nnz,
                                                        cnt_s, cnt_n, slot_s, slot_n);
    fused_k<<<B / 2, 256, 0, stream>>>(W2h, cnt_s, slot_s, cnt_n, slot_n,
                                       ft_b, fft_b, out_w, out_b, out, B);
}

// Round 4
// 165.329 us; speedup vs baseline: 1.0338x; 1.0338x over previous
//
#include <hip/hip_runtime.h>
#include <math.h>

#define FT_OUT 256
#define VFT 640
#define CAP 96  // per-row bucket capacity; Poisson(32) max ~56-60, 96 = +11 sigma

typedef _Float16 half8_t __attribute__((ext_vector_type(8)));
typedef float    float8_t __attribute__((ext_vector_type(8)));

// ---- merged prep: blocks [0, nbuild) build W2h; blocks [nbuild, ...) fill slots ----
// W2h[col][o] = (half)(ft_w[o][col] + fft_w[o][col%640])
__global__ __launch_bounds__(256) void prep_k(
    const float* __restrict__ ft_w, const float* __restrict__ fft_w,
    _Float16* __restrict__ W2h, int ft_in,
    const int* __restrict__ stm, const int* __restrict__ nstm,
    const float* __restrict__ vals, int nnz,
    int* __restrict__ cnt_s, int* __restrict__ cnt_n,
    int2* __restrict__ slot_s, int2* __restrict__ slot_n, int nbuild)
{
    if ((int)blockIdx.x < nbuild) {
        __shared__ float tile[64][65];  // [out][col]
        int bx = blockIdx.x;
        int cb = (bx >> 2) * 64;   // 640 col tiles
        int ob = (bx & 3) * 64;    // 4 out tiles
        int tc4 = threadIdx.x & 15, tr = threadIdx.x >> 4;
#pragma unroll
        for (int i = 0; i < 4; i++) {
            int o = i * 16 + tr;
            const float4 f = *(const float4*)(ft_w + (size_t)(ob + o) * ft_in + cb + tc4 * 4);
            tile[o][tc4 * 4 + 0] = f.x; tile[o][tc4 * 4 + 1] = f.y;
            tile[o][tc4 * 4 + 2] = f.z; tile[o][tc4 * 4 + 3] = f.w;
        }
        __syncthreads();
        int g = threadIdx.x & 7, cl = threadIdx.x >> 3;
#pragma unroll
        for (int i = 0; i < 2; i++) {
            int c = i * 32 + cl, col = cb + c, vcol = col % VFT;
            half8_t h;
#pragma unroll
            for (int jj = 0; jj < 8; jj++)
                h[jj] = (_Float16)(tile[g * 8 + jj][c] + fft_w[(size_t)(ob + g * 8 + jj) * VFT + vcol]);
            *(half8_t*)(W2h + (size_t)col * FT_OUT + ob + g * 8) = h;
        }
    } else {
        int k = ((int)blockIdx.x - nbuild) * 256 + threadIdx.x;
        if (k >= nnz) return;
        int vb = __float_as_int(vals[k]);
        int r = stm[k], c = stm[nnz + k];
        int pos = atomicAdd(&cnt_s[r], 1);
        if (pos < CAP) slot_s[(size_t)r * CAP + pos] = make_int2(c, vb);
        r = nstm[k]; c = nstm[nnz + k];
        pos = atomicAdd(&cnt_n[r], 1);
        if (pos < CAP) slot_n[(size_t)r * CAP + pos] = make_int2(c, vb);
    }
}

// ------- fused gather + clip + head + sigmoid: one wave per (row, side) -------
// Lane halves: lanes 0-31 process even slot entries, 32-63 odd; each lane loads
// half8 (16B) covering 8 outputs at chunk (lane&31).
__global__ __launch_bounds__(256) void fused_k(const _Float16* __restrict__ W2h,
    const int* __restrict__ cnt_s, const int2* __restrict__ slot_s,
    const int* __restrict__ cnt_n, const int2* __restrict__ slot_n,
    const float* __restrict__ ft_b, const float* __restrict__ fft_b,
    const float* __restrict__ out_w, const float* __restrict__ out_b,
    float* __restrict__ out, int B) {
    int lane = threadIdx.x & 63;
    int wid  = threadIdx.x >> 6;            // 0..3
    int row  = blockIdx.x * 2 + (wid >> 1); // 2 rows per block
    int side = wid & 1;                     // 0 = stm, 1 = nstm
    int hi   = lane >> 5;                   // 0 or 1: which slot entry of a pair
    int sl   = lane & 31;                   // 8-output chunk index

    const int*  cnt  = side ? cnt_n : cnt_s;
    const int2* slot = (side ? slot_n : slot_s) + (size_t)row * CAP;
    int n = min(cnt[row], CAP);

    float8_t acc;
#pragma unroll
    for (int k = 0; k < 8; k++) acc[k] = 0.f;
    if (hi == 0) {  // bias only once across the two halves
        const float4* fb = (const float4*)(ft_b + sl * 8);
        const float4* gb = (const float4*)(fft_b + sl * 8);
        float4 a0 = fb[0], a1 = fb[1], c0 = gb[0], c1 = gb[1];
        acc[0] = a0.x + c0.x; acc[1] = a0.y + c0.y; acc[2] = a0.z + c0.z; acc[3] = a0.w + c0.w;
        acc[4] = a1.x + c1.x; acc[5] = a1.y + c1.y; acc[6] = a1.z + c1.z; acc[7] = a1.w + c1.w;
    }

#define PROC(e)                                                                     \
    {                                                                               \
        int   c_ = hi ? (e).z : (e).x;                                              \
        float v_ = __int_as_float(hi ? (e).w : (e).y);                              \
        const half8_t w_ = *(const half8_t*)(W2h + ((size_t)c_ << 8) + (sl << 3));  \
        _Pragma("unroll")                                                           \
        for (int k = 0; k < 8; k++) acc[k] += v_ * (float)w_[k];                    \
    }

    int j = 0;
    for (; j + 8 <= n; j += 8) {  // 4 slot + 4 weight loads in flight
        const int4 e0 = *(const int4*)(slot + j);
        const int4 e1 = *(const int4*)(slot + j + 2);
        const int4 e2 = *(const int4*)(slot + j + 4);
        const int4 e3 = *(const int4*)(slot + j + 6);
        PROC(e0) PROC(e1) PROC(e2) PROC(e3)
    }
    for (; j + 2 <= n; j += 2) {
        const int4 e = *(const int4*)(slot + j);
        PROC(e)
    }
    if (j < n) {  // odd tail: high half contributes zero via dummy col 0
        const int2 e = slot[j];
        int   c_ = hi ? 0 : e.x;
        float v_ = hi ? 0.f : __int_as_float(e.y);
        const half8_t w_ = *(const half8_t*)(W2h + ((size_t)c_ << 8) + (sl << 3));
#pragma unroll
        for (int k = 0; k < 8; k++) acc[k] += v_ * (float)w_[k];
    }
#undef PROC

    // combine the two lane-halves (lane l and l^32 own the same 8 outputs), clip
#pragma unroll
    for (int k = 0; k < 8; k++) {
        float o = __shfl_xor(acc[k], 32, 64);
        acc[k] = fminf(fmaxf(acc[k] + o, 0.f), 1.f);
    }

    const float4* ow = (const float4*)(out_w + side * FT_OUT + sl * 8);
    const float4 w0 = ow[0], w1 = ow[1];
    float p = acc[0] * w0.x + acc[1] * w0.y + acc[2] * w0.z + acc[3] * w0.w
            + acc[4] * w1.x + acc[5] * w1.y + acc[6] * w1.z + acc[7] * w1.w;
#pragma unroll
    for (int m = 32; m >= 1; m >>= 1) p += __shfl_xor(p, m, 64);
    p *= 0.5f;  // both halves duplicated the per-chunk partials

    __shared__ float part[4];
    if (lane == 0) part[wid] = p;
    __syncthreads();
    if (threadIdx.x < 2) {
        float q = part[threadIdx.x * 2] + part[threadIdx.x * 2 + 1] + out_b[0];
        out[blockIdx.x * 2 + threadIdx.x] = 1.f / (1.f + __expf(-q));
    }
}

extern "C" void kernel_launch(void* const* d_in, const int* in_sizes, int n_in,
                              void* d_out, int out_size, void* d_ws, size_t ws_size,
                              hipStream_t stream) {
    const int*   stm    = (const int*)d_in[0];   // [2, NNZ]: rows then cols
    const int*   nstm   = (const int*)d_in[1];
    const float* values = (const float*)d_in[2];
    const float* ft_w   = (const float*)d_in[4];
    const float* ft_b   = (const float*)d_in[5];
    const float* fft_w  = (const float*)d_in[6];
    const float* fft_b  = (const float*)d_in[7];
    const float* out_w  = (const float*)d_in[8];
    const float* out_b  = (const float*)d_in[9];
    float* out = (float*)d_out;

    int B = out_size;                 // 8192
    int nnz = in_sizes[0] / 2;        // 262144
    int ft_in = in_sizes[4] / FT_OUT; // 40960

    // workspace layout (16B-aligned pieces)
    _Float16* W2h  = (_Float16*)d_ws;                          // ft_in*256 halfs (20 MB)
    int2*  slot_s  = (int2*)(W2h + (size_t)ft_in * FT_OUT);    // B*CAP entries (6 MB)
    int2*  slot_n  = slot_s + (size_t)B * CAP;                 // 6 MB
    int*   cnt_s   = (int*)(slot_n + (size_t)B * CAP);         // B
    int*   cnt_n   = cnt_s + B;                                // B

    int nbuild = (ft_in / 64) * (FT_OUT / 64);                 // 2560
    int nfill  = (nnz + 255) / 256;                            // 1024

    hipMemsetAsync(cnt_s, 0, 2 * (size_t)B * sizeof(int), stream);
    prep_k<<<nbuild + nfill, 256, 0, stream>>>(ft_w, fft_w, W2h, ft_in,
                                               stm, nstm, values, nnz,
                                               cnt_s, cnt_n, slot_s, slot_n, nbuild);
    fused_k<<<B / 2, 256, 0, stream>>>(W2h, cnt_s, slot_s, cnt_n, slot_n,
                                       ft_b, fft_b, out_w, out_b, out, B);
}

// Round 5
// 163.240 us; speedup vs baseline: 1.0470x; 1.0128x over previous
//
#include <hip/hip_runtime.h>
#include <math.h>

#define FT_OUT 256
#define VFT 640
#define CAP 96  // per-row bucket capacity; Poisson(32) max ~56-60, 96 = +11 sigma

typedef _Float16 half8_t __attribute__((ext_vector_type(8)));
typedef float    float8_t __attribute__((ext_vector_type(8)));

// ---- merged prep: blocks [0, nfill) fill slots; blocks [nfill, ...) build W2h ----
// Fill first: atomic-latency-bound work overlaps under build's streaming traffic.
// W2h[col][o] = (half)(ft_w[o][col] + fft_w[o][col%640])
__global__ __launch_bounds__(256) void prep_k(
    const float* __restrict__ ft_w, const float* __restrict__ fft_w,
    _Float16* __restrict__ W2h, int ft_in,
    const int* __restrict__ stm, const int* __restrict__ nstm,
    const float* __restrict__ vals, int nnz,
    int* __restrict__ cnt_s, int* __restrict__ cnt_n,
    int2* __restrict__ slot_s, int2* __restrict__ slot_n, int nfill)
{
    __shared__ float tile[64][65];   // ft  [out][col]
    __shared__ float ftile[64][65];  // fft [out][col]
    if ((int)blockIdx.x < nfill) {
        int k = (int)blockIdx.x * 256 + threadIdx.x;
        if (k >= nnz) return;
        int vb = __float_as_int(vals[k]);
        int r = stm[k], c = stm[nnz + k];
        int pos = atomicAdd(&cnt_s[r], 1);
        if (pos < CAP) slot_s[(size_t)r * CAP + pos] = make_int2(c, vb);
        r = nstm[k]; c = nstm[nnz + k];
        pos = atomicAdd(&cnt_n[r], 1);
        if (pos < CAP) slot_n[(size_t)r * CAP + pos] = make_int2(c, vb);
    } else {
        int bx = (int)blockIdx.x - nfill;
        int cb = (bx >> 2) * 64;     // 640 col tiles
        int ob = (bx & 3) * 64;      // 4 out tiles
        int fvb = cb % VFT;          // 640 % 64 == 0 -> contiguous 64-col window
        int tc4 = threadIdx.x & 15, tr = threadIdx.x >> 4;
#pragma unroll
        for (int i = 0; i < 4; i++) {
            int o = i * 16 + tr;
            const float4 f = *(const float4*)(ft_w + (size_t)(ob + o) * ft_in + cb + tc4 * 4);
            const float4 g = *(const float4*)(fft_w + (size_t)(ob + o) * VFT + fvb + tc4 * 4);
            tile[o][tc4 * 4 + 0] = f.x; tile[o][tc4 * 4 + 1] = f.y;
            tile[o][tc4 * 4 + 2] = f.z; tile[o][tc4 * 4 + 3] = f.w;
            ftile[o][tc4 * 4 + 0] = g.x; ftile[o][tc4 * 4 + 1] = g.y;
            ftile[o][tc4 * 4 + 2] = g.z; ftile[o][tc4 * 4 + 3] = g.w;
        }
        __syncthreads();
        int g = threadIdx.x & 7, cl = threadIdx.x >> 3;
#pragma unroll
        for (int i = 0; i < 2; i++) {
            int c = i * 32 + cl, col = cb + c;
            half8_t h;
#pragma unroll
            for (int jj = 0; jj < 8; jj++)
                h[jj] = (_Float16)(tile[g * 8 + jj][c] + ftile[g * 8 + jj][c]);
            *(half8_t*)(W2h + (size_t)col * FT_OUT + ob + g * 8) = h;
        }
    }
}

// ------- fused gather + clip + head + sigmoid: one wave per (row, side) -------
// Lane halves: lanes 0-31 process even slot entries, 32-63 odd; each lane loads
// half8 (16B) covering 8 outputs at chunk (lane&31).
__global__ __launch_bounds__(256) void fused_k(const _Float16* __restrict__ W2h,
    const int* __restrict__ cnt_s, const int2* __restrict__ slot_s,
    const int* __restrict__ cnt_n, const int2* __restrict__ slot_n,
    const float* __restrict__ ft_b, const float* __restrict__ fft_b,
    const float* __restrict__ out_w, const float* __restrict__ out_b,
    float* __restrict__ out, int B) {
    int lane = threadIdx.x & 63;
    int wid  = threadIdx.x >> 6;            // 0..3
    int row  = blockIdx.x * 2 + (wid >> 1); // 2 rows per block
    int side = wid & 1;                     // 0 = stm, 1 = nstm
    int hi   = lane >> 5;                   // 0 or 1: which slot entry of a pair
    int sl   = lane & 31;                   // 8-output chunk index

    const int*  cnt  = side ? cnt_n : cnt_s;
    const int2* slot = (side ? slot_n : slot_s) + (size_t)row * CAP;
    int n = min(cnt[row], CAP);

    float8_t acc;
#pragma unroll
    for (int k = 0; k < 8; k++) acc[k] = 0.f;
    if (hi == 0) {  // bias only once across the two halves
        const float4* fb = (const float4*)(ft_b + sl * 8);
        const float4* gb = (const float4*)(fft_b + sl * 8);
        float4 a0 = fb[0], a1 = fb[1], c0 = gb[0], c1 = gb[1];
        acc[0] = a0.x + c0.x; acc[1] = a0.y + c0.y; acc[2] = a0.z + c0.z; acc[3] = a0.w + c0.w;
        acc[4] = a1.x + c1.x; acc[5] = a1.y + c1.y; acc[6] = a1.z + c1.z; acc[7] = a1.w + c1.w;
    }

#define PROC(e)                                                                     \
    {                                                                               \
        int   c_ = hi ? (e).z : (e).x;                                              \
        float v_ = __int_as_float(hi ? (e).w : (e).y);                              \
        const half8_t w_ = *(const half8_t*)(W2h + ((size_t)c_ << 8) + (sl << 3));  \
        _Pragma("unroll")                                                           \
        for (int k = 0; k < 8; k++) acc[k] += v_ * (float)w_[k];                    \
    }

    int j = 0;
    for (; j + 8 <= n; j += 8) {  // 4 slot + 4 weight loads in flight
        const int4 e0 = *(const int4*)(slot + j);
        const int4 e1 = *(const int4*)(slot + j + 2);
        const int4 e2 = *(const int4*)(slot + j + 4);
        const int4 e3 = *(const int4*)(slot + j + 6);
        PROC(e0) PROC(e1) PROC(e2) PROC(e3)
    }
    for (; j + 2 <= n; j += 2) {
        const int4 e = *(const int4*)(slot + j);
        PROC(e)
    }
    if (j < n) {  // odd tail: high half contributes zero via dummy col 0
        const int2 e = slot[j];
        int   c_ = hi ? 0 : e.x;
        float v_ = hi ? 0.f : __int_as_float(e.y);
        const half8_t w_ = *(const half8_t*)(W2h + ((size_t)c_ << 8) + (sl << 3));
#pragma unroll
        for (int k = 0; k < 8; k++) acc[k] += v_ * (float)w_[k];
    }
#undef PROC

    // combine the two lane-halves (lane l and l^32 own the same 8 outputs), clip
#pragma unroll
    for (int k = 0; k < 8; k++) {
        float o = __shfl_xor(acc[k], 32, 64);
        acc[k] = fminf(fmaxf(acc[k] + o, 0.f), 1.f);
    }

    const float4* ow = (const float4*)(out_w + side * FT_OUT + sl * 8);
    const float4 w0 = ow[0], w1 = ow[1];
    float p = acc[0] * w0.x + acc[1] * w0.y + acc[2] * w0.z + acc[3] * w0.w
            + acc[4] * w1.x + acc[5] * w1.y + acc[6] * w1.z + acc[7] * w1.w;
#pragma unroll
    for (int m = 32; m >= 1; m >>= 1) p += __shfl_xor(p, m, 64);
    p *= 0.5f;  // both halves duplicated the per-chunk partials

    __shared__ float part[4];
    if (lane == 0) part[wid] = p;
    __syncthreads();
    if (threadIdx.x < 2) {
        float q = part[threadIdx.x * 2] + part[threadIdx.x * 2 + 1] + out_b[0];
        out[blockIdx.x * 2 + threadIdx.x] = 1.f / (1.f + __expf(-q));
    }
}

extern "C" void kernel_launch(void* const* d_in, const int* in_sizes, int n_in,
                              void* d_out, int out_size, void* d_ws, size_t ws_size,
                              hipStream_t stream) {
    const int*   stm    = (const int*)d_in[0];   // [2, NNZ]: rows then cols
    const int*   nstm   = (const int*)d_in[1];
    const float* values = (const float*)d_in[2];
    const float* ft_w   = (const float*)d_in[4];
    const float* ft_b   = (const float*)d_in[5];
    const float* fft_w  = (const float*)d_in[6];
    const float* fft_b  = (const float*)d_in[7];
    const float* out_w  = (const float*)d_in[8];
    const float* out_b  = (const float*)d_in[9];
    float* out = (float*)d_out;

    int B = out_size;                 // 8192
    int nnz = in_sizes[0] / 2;        // 262144
    int ft_in = in_sizes[4] / FT_OUT; // 40960

    // workspace layout (16B-aligned pieces)
    _Float16* W2h  = (_Float16*)d_ws;                          // ft_in*256 halfs (20 MB)
    int2*  slot_s  = (int2*)(W2h + (size_t)ft_in * FT_OUT);    // B*CAP entries (6 MB)
    int2*  slot_n  = slot_s + (size_t)B * CAP;                 // 6 MB
    int*   cnt_s   = (int*)(slot_n + (size_t)B * CAP);         // B
    int*   cnt_n   = cnt_s + B;                                // B

    int nbuild = (ft_in / 64) * (FT_OUT / 64);                 // 2560
    int nfill  = (nnz + 255) / 256;                            // 1024

    hipMemsetAsync(cnt_s, 0, 2 * (size_t)B * sizeof(int), stream);
    prep_k<<<nfill + nbuild, 256, 0, stream>>>(ft_w, fft_w, W2h, ft_in,
                                               stm, nstm, values, nnz,
                                               cnt_s, cnt_n, slot_s, slot_n, nfill);
    fused_k<<<B / 2, 256, 0, stream>>>(W2h, cnt_s, slot_s, cnt_n, slot_n,
                                       ft_b, fft_b, out_w, out_b, out, B);
}